// Round 8
// baseline (256.750 us; speedup 1.0000x reference)
//
#include <hip/hip_runtime.h>
#include <math.h>

#define DEV __device__ __forceinline__

namespace {

constexpr int Bb  = 2;
constexpr int Nn  = 4096;   // H*W tokens per batch
constexpr int Cc  = 19;     // prob channels
constexpr int NHh = 4;      // heads
constexpr int SEGS = 4;     // attention split-K segments
constexpr float EPSv = 1e-5f;
constexpr float LOG2E = 1.4426950408889634f;

typedef __attribute__((ext_vector_type(4))) short short4v;
typedef __attribute__((ext_vector_type(8))) short short8v;
typedef __attribute__((ext_vector_type(4))) float f32x4;
typedef unsigned short ushort_t;
typedef unsigned int uint_t;

// workspace layout (float offsets)
constexpr size_t QKV_F    = (size_t)Bb * Nn * 32;           // 262144
constexpr size_t OFF_XSEQ = 0;                              // B*N*64 f32
constexpr size_t OFF_XATT = OFF_XSEQ + (size_t)Bb*Nn*64;
constexpr size_t OFF_QB   = OFF_XATT + (size_t)Bb*Nn*64;    // bf16 [B*NH][N][16]
constexpr size_t OFF_KB   = OFF_QB + QKV_F;
constexpr size_t OFF_VB   = OFF_KB + QKV_F;
constexpr size_t OFF_VT   = OFF_VB + QKV_F;                 // bf16 [B*NH][16][N]
constexpr size_t OFF_MP   = OFF_VT + QKV_F;                 // [bh][seg][q]
constexpr size_t OFF_LP   = OFF_MP + (size_t)Bb*NHh*SEGS*Nn;
constexpr size_t OFF_OP   = OFF_LP + (size_t)Bb*NHh*SEGS*Nn; // [bh][seg][q][16]
constexpr size_t OFF_XN2  = OFF_OP + (size_t)Bb*NHh*SEGS*Nn*16; // bf16 [8192][64]
constexpr size_t OFF_GW   = OFF_XN2 + (size_t)Bb*Nn*32;     // f32 [8192][4]
constexpr size_t OFF_H1   = OFF_GW + (size_t)Bb*Nn*4;       // bf16 [8192][512]
constexpr size_t OFF_W1T  = OFF_H1 + (size_t)Bb*Nn*256;     // bf16 [512][64]
constexpr size_t OFF_W2T  = OFF_W1T + 16384;                // bf16 [64][512]
// end ~= 27.6 MB

DEV float wredsum(float x) {
  #pragma unroll
  for (int off = 32; off > 0; off >>= 1) x += __shfl_xor(x, off, 64);
  return x;
}
// f32 -> bf16 RNE via bit ops (finite inputs only)
DEV ushort_t f2bf(float x) {
  uint_t u = __builtin_bit_cast(uint_t, x);
  u += 0x7fffu + ((u >> 16) & 1u);
  return (ushort_t)(u >> 16);
}
// packed 2xbf16 via HW cvt_pk (a in low half), RNE
DEV uint_t cvtpk(float a, float b) {
  uint_t r;
  asm("v_cvt_pk_bf16_f32 %0, %1, %2" : "=v"(r) : "v"(a), "v"(b));
  return r;
}

// ---------------------------------------------------------------------------
// K0: expert weights -> transposed bf16 tables.
// W1T[col][k]  col=e*128+h, k=d   (from w1[e][d][h])
// W2T[d][kk]   kk=e*128+h         (from w2[e][h][d])
// ---------------------------------------------------------------------------
__global__ __launch_bounds__(256) void k_wcvt(
    const float* __restrict__ w1, const float* __restrict__ w2,
    float* __restrict__ ws)
{
  const int idx = blockIdx.x * 256 + threadIdx.x;   // 0..32767
  ushort_t* w1t = (ushort_t*)(ws + OFF_W1T);
  ushort_t* w2t = (ushort_t*)(ws + OFF_W2T);
  {
    const int col = idx >> 6, k = idx & 63;
    const int e = col >> 7, h = col & 127;
    w1t[idx] = f2bf(w1[((size_t)e * 64 + k) * 128 + h]);
  }
  {
    const int d = idx >> 9, kk = idx & 511;
    const int e = kk >> 7, h = kk & 127;
    w2t[idx] = f2bf(w2[((size_t)e * 128 + h) * 64 + d]);
  }
}

// ---------------------------------------------------------------------------
// K1: embed -> x_seq -> LN1 -> QKV (bf16; Q prescaled by 0.25*log2e)
// ---------------------------------------------------------------------------
__global__ __launch_bounds__(256) void k_embed_qkv(
    const float* __restrict__ depth, const float* __restrict__ prob,
    const float* __restrict__ emb_w, const float* __restrict__ emb_b,
    const float* __restrict__ ipw,   const float* __restrict__ ipb,
    const float* __restrict__ ln1g,  const float* __restrict__ ln1b,
    float* __restrict__ ws)
{
  __shared__ float ipws[64 * 192];   // 48 KB

  const int t = threadIdx.x;
  #pragma unroll
  for (int i = 0; i < 12; ++i) {
    const int idx = (i * 256 + t) * 4;
    *(float4*)&ipws[idx] = *(const float4*)&ipw[idx];
  }

  const int lane = t & 63;
  const int wid  = t >> 6;
  const int tok  = blockIdx.x * 4 + wid;
  const int b = tok >> 12, n = tok & (Nn - 1);
  const int d = lane;

  float acc = emb_b[d];
  acc += depth[(size_t)b * Nn + n] * emb_w[d];
  #pragma unroll
  for (int c = 0; c < Cc; ++c)
    acc += prob[((size_t)b * Cc + c) * Nn + n] * emb_w[(1 + c) * 64 + d];

  ws[OFF_XSEQ + (size_t)tok * 64 + d] = acc;

  float mean = wredsum(acc) * (1.f / 64.f);
  float diff = acc - mean;
  float var  = wredsum(diff * diff) * (1.f / 64.f);
  float xn   = diff * rsqrtf(var + EPSv) * ln1g[d] + ln1b[d];

  __syncthreads();   // ipws ready

  float aq = ipb[d], ak = ipb[64 + d], av = ipb[128 + d];
  #pragma unroll 8
  for (int j = 0; j < 64; ++j) {
    float xj = __shfl(xn, j, 64);
    const float* wr = ipws + j * 192;
    aq = fmaf(xj, wr[d],       aq);
    ak = fmaf(xj, wr[64 + d],  ak);
    av = fmaf(xj, wr[128 + d], av);
  }
  const int h = d >> 4, dd = d & 15;
  ushort_t* qb = (ushort_t*)(ws + OFF_QB);
  ushort_t* kb = (ushort_t*)(ws + OFF_KB);
  ushort_t* vb = (ushort_t*)(ws + OFF_VB);
  const size_t base = ((size_t)(b * NHh + h) * Nn + n) * 16 + dd;
  qb[base] = f2bf(aq * 0.25f * LOG2E);
  kb[base] = f2bf(ak);
  vb[base] = f2bf(av);
}

// ---------------------------------------------------------------------------
// K1b: transpose V bf16 [bh][N][16] -> [bh][16][N]
// ---------------------------------------------------------------------------
__global__ __launch_bounds__(256) void k_transpose_v(float* __restrict__ ws)
{
  __shared__ ushort_t tile[256][17];
  const ushort_t* vb = (const ushort_t*)(ws + OFF_VB);
  ushort_t*       vt = (ushort_t*)(ws + OFF_VT);
  const int bh = blockIdx.y;
  const int n0 = blockIdx.x * 256;
  const int t  = threadIdx.x;

  const ushort_t* src = vb + ((size_t)bh * Nn + n0 + t) * 16;
  short8v r0 = *(const short8v*)(src);
  short8v r1 = *(const short8v*)(src + 8);
  #pragma unroll
  for (int i = 0; i < 8; ++i) { tile[t][i] = (ushort_t)r0[i]; tile[t][8 + i] = (ushort_t)r1[i]; }
  __syncthreads();

  const int d = t & 15, seg = t >> 4;
  short8v w0, w1;
  #pragma unroll
  for (int i = 0; i < 8; ++i) {
    w0[i] = (short)tile[seg * 16 + i][d];
    w1[i] = (short)tile[seg * 16 + 8 + i][d];
  }
  ushort_t* dst = vt + ((size_t)bh * 16 + d) * Nn + n0 + seg * 16;
  *(short8v*)(dst)     = w0;
  *(short8v*)(dst + 8) = w1;
}

// ---------------------------------------------------------------------------
// K2: MFMA flash attention, split-K x4 (16 chunks of 64 k per wave).
// launch_bounds(256,8): 8 blocks/CU -> 32 waves/CU for latency hiding.
// ---------------------------------------------------------------------------
__global__ __launch_bounds__(256, 8) void k_attn_mfma(float* __restrict__ ws)
{
  const int lane = threadIdx.x & 63;
  const int wid  = threadIdx.x >> 6;
  const int blk  = blockIdx.x;
  const int seg  = blockIdx.y;              // 0..SEGS-1
  const int bh   = blk >> 6;
  const int qt   = (blk & 63) * 4 + wid;
  const int q0   = qt * 16;
  const int g    = lane >> 4;
  const int qi   = lane & 15;

  const ushort_t* qb = (const ushort_t*)(ws + OFF_QB) + (size_t)bh * Nn * 16;
  const ushort_t* kb = (const ushort_t*)(ws + OFF_KB) + (size_t)bh * Nn * 16;
  const ushort_t* vt = (const ushort_t*)(ws + OFF_VT) + (size_t)bh * 16 * Nn;

  short8v qf = {};
  if (lane < 32)
    qf = *(const short8v*)(qb + (size_t)(q0 + qi) * 16 + g * 8);

  f32x4 O = {0.f, 0.f, 0.f, 0.f};
  float mrun = -INFINITY;
  float lacc[16];
  #pragma unroll
  for (int i = 0; i < 16; ++i) lacc[i] = 0.f;
  const f32x4 z4 = {0.f, 0.f, 0.f, 0.f};
  const ushort_t* vrow = vt + (size_t)qi * Nn;

  const int c0 = seg * (Nn / 64 / SEGS);
  #pragma unroll 2
  for (int c = c0; c < c0 + Nn / 64 / SEGS; ++c) {
    const int kb0 = c * 64;
    short8v kf0 = {}, kf1 = {}, kf2 = {}, kf3 = {};
    if (lane < 32) {
      const ushort_t* kr = kb + (size_t)(kb0 + qi) * 16 + g * 8;
      kf0 = *(const short8v*)(kr);
      kf1 = *(const short8v*)(kr + 256);
      kf2 = *(const short8v*)(kr + 512);
      kf3 = *(const short8v*)(kr + 768);
    }
    const ushort_t* vr = vrow + kb0 + 4 * g;
    short4v va00 = *(const short4v*)(vr);
    short4v va01 = *(const short4v*)(vr + 16);
    short4v va10 = *(const short4v*)(vr + 32);
    short4v va11 = *(const short4v*)(vr + 48);

    f32x4 s0 = __builtin_amdgcn_mfma_f32_16x16x32_bf16(kf0, qf, z4, 0, 0, 0);
    f32x4 s1 = __builtin_amdgcn_mfma_f32_16x16x32_bf16(kf1, qf, z4, 0, 0, 0);
    f32x4 s2 = __builtin_amdgcn_mfma_f32_16x16x32_bf16(kf2, qf, z4, 0, 0, 0);
    f32x4 s3 = __builtin_amdgcn_mfma_f32_16x16x32_bf16(kf3, qf, z4, 0, 0, 0);

    float cm = fmaxf(fmaxf(fmaxf(s0[0], s0[1]), fmaxf(s0[2], s0[3])),
                     fmaxf(fmaxf(s1[0], s1[1]), fmaxf(s1[2], s1[3])));
    cm = fmaxf(cm, fmaxf(fmaxf(s2[0], s2[1]), fmaxf(s2[2], s2[3])));
    cm = fmaxf(cm, fmaxf(fmaxf(s3[0], s3[1]), fmaxf(s3[2], s3[3])));
    cm = fmaxf(cm, __shfl_xor(cm, 16, 64));
    cm = fmaxf(cm, __shfl_xor(cm, 32, 64));

    // defer-max (T13), log2 domain
    if (!__all(cm <= mrun + 11.5f)) {
      const float nm = fmaxf(mrun, cm);
      const float c2 = exp2f(mrun - nm);   // exp2(-inf)=0 handles init
      #pragma unroll
      for (int i = 0; i < 16; ++i) lacc[i] *= c2;
      O[0] *= c2; O[1] *= c2; O[2] *= c2; O[3] *= c2;
      mrun = nm;
    }

    float p[16];
    #pragma unroll
    for (int r = 0; r < 4; ++r) {
      p[r]      = exp2f(s0[r] - mrun);
      p[4 + r]  = exp2f(s1[r] - mrun);
      p[8 + r]  = exp2f(s2[r] - mrun);
      p[12 + r] = exp2f(s3[r] - mrun);
    }
    #pragma unroll
    for (int i = 0; i < 16; ++i) lacc[i] += p[i];

    union { short8v v; uint_t w[4]; } P0, P1;
    P0.w[0] = cvtpk(p[0], p[1]);   P0.w[1] = cvtpk(p[2], p[3]);
    P0.w[2] = cvtpk(p[4], p[5]);   P0.w[3] = cvtpk(p[6], p[7]);
    P1.w[0] = cvtpk(p[8], p[9]);   P1.w[1] = cvtpk(p[10], p[11]);
    P1.w[2] = cvtpk(p[12], p[13]); P1.w[3] = cvtpk(p[14], p[15]);

    union { short8v v; short4v hh[2]; } VA0, VA1;
    VA0.hh[0] = va00; VA0.hh[1] = va01;
    VA1.hh[0] = va10; VA1.hh[1] = va11;

    O = __builtin_amdgcn_mfma_f32_16x16x32_bf16(VA0.v, P0.v, O, 0, 0, 0);
    O = __builtin_amdgcn_mfma_f32_16x16x32_bf16(VA1.v, P1.v, O, 0, 0, 0);
  }

  float lrun = 0.f;
  #pragma unroll
  for (int i = 0; i < 16; ++i) lrun += lacc[i];
  lrun += __shfl_xor(lrun, 16, 64);
  lrun += __shfl_xor(lrun, 32, 64);

  const size_t pb = ((size_t)bh * SEGS + seg) * Nn + q0 + qi;
  if (g == 0) { ws[OFF_MP + pb] = mrun; ws[OFF_LP + pb] = lrun; }
  f32x4* op = (f32x4*)(ws + OFF_OP + pb * 16 + g * 4);
  *op = O;
}

// ---------------------------------------------------------------------------
// K3: merge SEGS partials -> out-proj + residual -> x_att -> LN2 -> gate.
// one wave per token; lane = d (= h*16+dd for the merge phase).
// ---------------------------------------------------------------------------
__global__ __launch_bounds__(256) void k_out_ln2(
    const float* __restrict__ aow,  const float* __restrict__ aob,
    const float* __restrict__ ln2g, const float* __restrict__ ln2b,
    const float* __restrict__ gwt,  const float* __restrict__ gbt,
    float* __restrict__ ws)
{
  __shared__ float aows[64 * 64];   // 16 KB
  const int t = threadIdx.x;
  #pragma unroll
  for (int i = 0; i < 4; ++i) {
    const int idx = (i * 256 + t) * 4;
    *(float4*)&aows[idx] = *(const float4*)&aow[idx];
  }

  const int lane = t & 63;
  const int wid  = t >> 6;
  const int tok  = blockIdx.x * 4 + wid;
  const int b = tok >> 12, n = tok & (Nn - 1);
  const int h = lane >> 4, dd = lane & 15;
  const int bh = b * NHh + h;

  float M = -INFINITY;
  #pragma unroll
  for (int s = 0; s < SEGS; ++s)
    M = fmaxf(M, ws[OFF_MP + ((size_t)bh * SEGS + s) * Nn + n]);
  float L = 0.f, oa = 0.f;
  #pragma unroll
  for (int s = 0; s < SEGS; ++s) {
    const size_t pb = ((size_t)bh * SEGS + s) * Nn + n;
    const float c = exp2f(ws[OFF_MP + pb] - M);
    L  = fmaf(ws[OFF_LP + pb], c, L);
    oa = fmaf(ws[OFF_OP + pb * 16 + dd], c, oa);
  }
  const float o = oa / L;

  __syncthreads();   // aows ready

  float acc = aob[lane];
  #pragma unroll 8
  for (int j = 0; j < 64; ++j)
    acc = fmaf(__shfl(o, j, 64), aows[j * 64 + lane], acc);
  const size_t xi = (size_t)tok * 64 + lane;
  const float xa = ws[OFF_XSEQ + xi] + acc;
  ws[OFF_XATT + xi] = xa;

  // LN2 + gate (lane = d)
  float mean = wredsum(xa) * (1.f / 64.f);
  float diff = xa - mean;
  float var  = wredsum(diff * diff) * (1.f / 64.f);
  float xn   = diff * rsqrtf(var + EPSv) * ln2g[lane] + ln2b[lane];

  ushort_t* xn2 = (ushort_t*)(ws + OFF_XN2);
  xn2[xi] = f2bf(xn);

  float ge[4];
  #pragma unroll
  for (int e = 0; e < 4; ++e) ge[e] = xn * gwt[lane * 4 + e];
  #pragma unroll
  for (int off = 32; off > 0; off >>= 1) {
    #pragma unroll
    for (int e = 0; e < 4; ++e) ge[e] += __shfl_xor(ge[e], off, 64);
  }
  #pragma unroll
  for (int e = 0; e < 4; ++e) ge[e] += gbt[e];
  float gm = fmaxf(fmaxf(ge[0], ge[1]), fmaxf(ge[2], ge[3]));
  float gs = 0.f;
  #pragma unroll
  for (int e = 0; e < 4; ++e) { ge[e] = __expf(ge[e] - gm); gs += ge[e]; }
  if (lane == 0) {
    float* gw = ws + OFF_GW + (size_t)tok * 4;
    #pragma unroll
    for (int e = 0; e < 4; ++e) gw[e] = ge[e] / gs;
  }
}

// ---------------------------------------------------------------------------
// K4: GEMM1  h1 = gw .* relu(xn2 @ W1all + b1)   [8192 x 512], K=64, bf16
// ---------------------------------------------------------------------------
__global__ __launch_bounds__(256) void k_gemm1(
    const float* __restrict__ eb1, float* __restrict__ ws)
{
  const int lane = threadIdx.x & 63;
  const int wid  = threadIdx.x >> 6;
  const int qi = lane & 15, g = lane >> 4;
  const int tok0 = blockIdx.x * 64 + wid * 16;
  const int col0 = blockIdx.y * 64;

  const ushort_t* xn2 = (const ushort_t*)(ws + OFF_XN2);
  const ushort_t* w1t = (const ushort_t*)(ws + OFF_W1T);
  const float* gw = ws + OFF_GW;
  ushort_t* h1 = (ushort_t*)(ws + OFF_H1);

  const short8v a0 = *(const short8v*)(xn2 + (size_t)(tok0 + qi) * 64 + g * 8);
  const short8v a1 = *(const short8v*)(xn2 + (size_t)(tok0 + qi) * 64 + 32 + g * 8);

  f32x4 acc[4] = {{0,0,0,0},{0,0,0,0},{0,0,0,0},{0,0,0,0}};
  #pragma unroll
  for (int cf = 0; cf < 4; ++cf) {
    const int col = col0 + cf * 16 + qi;
    const short8v b0 = *(const short8v*)(w1t + (size_t)col * 64 + g * 8);
    const short8v b1 = *(const short8v*)(w1t + (size_t)col * 64 + 32 + g * 8);
    acc[cf] = __builtin_amdgcn_mfma_f32_16x16x32_bf16(a0, b0, acc[cf], 0, 0, 0);
    acc[cf] = __builtin_amdgcn_mfma_f32_16x16x32_bf16(a1, b1, acc[cf], 0, 0, 0);
  }
  #pragma unroll
  for (int cf = 0; cf < 4; ++cf) {
    const int col = col0 + cf * 16 + qi;
    const int e = col >> 7;
    const float bb = eb1[col];
    #pragma unroll
    for (int r = 0; r < 4; ++r) {
      const int tok = tok0 + g * 4 + r;
      float v = fmaxf(acc[cf][r] + bb, 0.f) * gw[(size_t)tok * 4 + e];
      h1[(size_t)tok * 512 + col] = f2bf(v);
    }
  }
}

// ---------------------------------------------------------------------------
// K5: GEMM2 + b2 + residual + proj + sigmoid -> out.
// one wave (64 thr) per 16 tokens, full d=64.
// ---------------------------------------------------------------------------
__global__ __launch_bounds__(64) void k_gemm2f(
    const float* __restrict__ b2, const float* __restrict__ pw,
    const float* __restrict__ pbv, const float* __restrict__ ws,
    float* __restrict__ out)
{
  const int lane = threadIdx.x;
  const int qi = lane & 15, g = lane >> 4;
  const int tok0 = blockIdx.x * 16;

  const ushort_t* h1  = (const ushort_t*)(ws + OFF_H1);
  const ushort_t* w2t = (const ushort_t*)(ws + OFF_W2T);

  f32x4 acc[4] = {{0,0,0,0},{0,0,0,0},{0,0,0,0},{0,0,0,0}};
  #pragma unroll 4
  for (int s = 0; s < 16; ++s) {
    const short8v a = *(const short8v*)(h1 + (size_t)(tok0 + qi) * 512 + s * 32 + g * 8);
    #pragma unroll
    for (int cf = 0; cf < 4; ++cf) {
      const short8v b = *(const short8v*)(w2t + (size_t)(cf * 16 + qi) * 512 + s * 32 + g * 8);
      acc[cf] = __builtin_amdgcn_mfma_f32_16x16x32_bf16(a, b, acc[cf], 0, 0, 0);
    }
  }

  const float* xatt = ws + OFF_XATT;
  const float* gw   = ws + OFF_GW;

  float gwv[4][4];   // [r][e]
  #pragma unroll
  for (int r = 0; r < 4; ++r) {
    const int tok = tok0 + g * 4 + r;
    #pragma unroll
    for (int e = 0; e < 4; ++e) gwv[r][e] = gw[(size_t)tok * 4 + e];
  }

  float part[4] = {0.f, 0.f, 0.f, 0.f};
  #pragma unroll
  for (int cf = 0; cf < 4; ++cf) {
    const int d = cf * 16 + qi;
    const float pwd = pw[d];
    const float b20 = b2[d], b21 = b2[64 + d], b22 = b2[128 + d], b23 = b2[192 + d];
    #pragma unroll
    for (int r = 0; r < 4; ++r) {
      const int tok = tok0 + g * 4 + r;
      const float bias2 = gwv[r][0]*b20 + gwv[r][1]*b21 + gwv[r][2]*b22 + gwv[r][3]*b23;
      const float xo = xatt[(size_t)tok * 64 + d] + acc[cf][r] + bias2;
      part[r] = fmaf(xo, pwd, part[r]);
    }
  }
  // reduce over qi within each 16-lane group
  #pragma unroll
  for (int r = 0; r < 4; ++r) {
    #pragma unroll
    for (int mask = 8; mask > 0; mask >>= 1)
      part[r] += __shfl_xor(part[r], mask, 64);
  }
  if (qi == 0) {
    const float pb0 = pbv[0];
    #pragma unroll
    for (int r = 0; r < 4; ++r)
      out[tok0 + g * 4 + r] = 1.f / (1.f + __expf(-(part[r] + pb0)));
  }
}

} // namespace

extern "C" void kernel_launch(void* const* d_in, const int* in_sizes, int n_in,
                              void* d_out, int out_size, void* d_ws, size_t ws_size,
                              hipStream_t stream) {
  const float* depth = (const float*)d_in[0];
  const float* prob  = (const float*)d_in[1];
  const float* emb_w = (const float*)d_in[2];
  const float* emb_b = (const float*)d_in[3];
  const float* ipw   = (const float*)d_in[4];
  const float* ipb   = (const float*)d_in[5];
  const float* aow   = (const float*)d_in[6];
  const float* aob   = (const float*)d_in[7];
  const float* ln1g  = (const float*)d_in[8];
  const float* ln1b  = (const float*)d_in[9];
  const float* ln2g  = (const float*)d_in[10];
  const float* ln2b  = (const float*)d_in[11];
  const float* w1    = (const float*)d_in[12];
  const float* b1    = (const float*)d_in[13];
  const float* w2    = (const float*)d_in[14];
  const float* b2    = (const float*)d_in[15];
  const float* gatew = (const float*)d_in[16];
  const float* gateb = (const float*)d_in[17];
  const float* projw = (const float*)d_in[18];
  const float* projb = (const float*)d_in[19];
  float* out = (float*)d_out;
  float* wsf = (float*)d_ws;

  k_wcvt<<<128, 256, 0, stream>>>(w1, w2, wsf);
  k_embed_qkv<<<Bb * Nn / 4, 256, 0, stream>>>(depth, prob, emb_w, emb_b,
                                               ipw, ipb, ln1g, ln1b, wsf);
  k_transpose_v<<<dim3(Nn / 256, Bb * NHh), 256, 0, stream>>>(wsf);
  k_attn_mfma<<<dim3(Bb * NHh * 64, SEGS), 256, 0, stream>>>(wsf);
  k_out_ln2<<<Bb * Nn / 4, 256, 0, stream>>>(aow, aob, ln2g, ln2b,
                                             gatew, gateb, wsf);
  k_gemm1<<<dim3(Bb * Nn / 64, 8), 256, 0, stream>>>(b1, wsf);
  k_gemm2f<<<Bb * Nn / 16, 64, 0, stream>>>(b2, projw, projb, wsf, out);
}

// Round 9
// 231.671 us; speedup vs baseline: 1.1083x; 1.1083x over previous
//
#include <hip/hip_runtime.h>
#include <math.h>

#define DEV __device__ __forceinline__

namespace {

constexpr int Bb  = 2;
constexpr int Nn  = 4096;   // H*W tokens per batch
constexpr int Cc  = 19;     // prob channels
constexpr int NHh = 4;      // heads
constexpr int SEGS = 4;     // attention split-K segments
constexpr float EPSv = 1e-5f;
constexpr float LOG2E = 1.4426950408889634f;

typedef __attribute__((ext_vector_type(4))) short short4v;
typedef __attribute__((ext_vector_type(8))) short short8v;
typedef __attribute__((ext_vector_type(4))) float f32x4;
typedef unsigned short ushort_t;
typedef unsigned int uint_t;

// workspace layout (float offsets)
constexpr size_t QKV_F    = (size_t)Bb * Nn * 32;           // 262144
constexpr size_t OFF_XSEQ = 0;                              // B*N*64 f32
constexpr size_t OFF_XATT = OFF_XSEQ + (size_t)Bb*Nn*64;
constexpr size_t OFF_QB   = OFF_XATT + (size_t)Bb*Nn*64;    // bf16 [B*NH][N][16]
constexpr size_t OFF_KB   = OFF_QB + QKV_F;
constexpr size_t OFF_VB   = OFF_KB + QKV_F;
constexpr size_t OFF_VT   = OFF_VB + QKV_F;                 // bf16 [B*NH][16][N]
constexpr size_t OFF_MP   = OFF_VT + QKV_F;                 // [bh][seg][q]
constexpr size_t OFF_LP   = OFF_MP + (size_t)Bb*NHh*SEGS*Nn;
constexpr size_t OFF_OP   = OFF_LP + (size_t)Bb*NHh*SEGS*Nn; // [bh][seg][q][16]
constexpr size_t OFF_XN2  = OFF_OP + (size_t)Bb*NHh*SEGS*Nn*16; // bf16 [8192][64]
constexpr size_t OFF_GW   = OFF_XN2 + (size_t)Bb*Nn*32;     // f32 [8192][4]
constexpr size_t OFF_H1   = OFF_GW + (size_t)Bb*Nn*4;       // bf16 [8192][512]
constexpr size_t OFF_W1T  = OFF_H1 + (size_t)Bb*Nn*256;     // bf16 [512][64]
constexpr size_t OFF_W2T  = OFF_W1T + 16384;                // bf16 [64][512]
// end ~= 27.6 MB

DEV float wredsum(float x) {
  #pragma unroll
  for (int off = 32; off > 0; off >>= 1) x += __shfl_xor(x, off, 64);
  return x;
}
// f32 -> bf16 RNE via bit ops (finite inputs only)
DEV ushort_t f2bf(float x) {
  uint_t u = __builtin_bit_cast(uint_t, x);
  u += 0x7fffu + ((u >> 16) & 1u);
  return (ushort_t)(u >> 16);
}
// packed 2xbf16 via HW cvt_pk (a in low half), RNE
DEV uint_t cvtpk(float a, float b) {
  uint_t r;
  asm("v_cvt_pk_bf16_f32 %0, %1, %2" : "=v"(r) : "v"(a), "v"(b));
  return r;
}

// ---------------------------------------------------------------------------
// K0: expert weights -> transposed bf16 tables.
// ---------------------------------------------------------------------------
__global__ __launch_bounds__(256) void k_wcvt(
    const float* __restrict__ w1, const float* __restrict__ w2,
    float* __restrict__ ws)
{
  const int idx = blockIdx.x * 256 + threadIdx.x;   // 0..32767
  ushort_t* w1t = (ushort_t*)(ws + OFF_W1T);
  ushort_t* w2t = (ushort_t*)(ws + OFF_W2T);
  {
    const int col = idx >> 6, k = idx & 63;
    const int e = col >> 7, h = col & 127;
    w1t[idx] = f2bf(w1[((size_t)e * 64 + k) * 128 + h]);
  }
  {
    const int d = idx >> 9, kk = idx & 511;
    const int e = kk >> 7, h = kk & 127;
    w2t[idx] = f2bf(w2[((size_t)e * 128 + h) * 64 + d]);
  }
}

// ---------------------------------------------------------------------------
// K1: embed -> x_seq -> LN1 -> QKV (bf16; Q prescaled by 0.25*log2e)
// ---------------------------------------------------------------------------
__global__ __launch_bounds__(256) void k_embed_qkv(
    const float* __restrict__ depth, const float* __restrict__ prob,
    const float* __restrict__ emb_w, const float* __restrict__ emb_b,
    const float* __restrict__ ipw,   const float* __restrict__ ipb,
    const float* __restrict__ ln1g,  const float* __restrict__ ln1b,
    float* __restrict__ ws)
{
  __shared__ float ipws[64 * 192];   // 48 KB

  const int t = threadIdx.x;
  #pragma unroll
  for (int i = 0; i < 12; ++i) {
    const int idx = (i * 256 + t) * 4;
    *(float4*)&ipws[idx] = *(const float4*)&ipw[idx];
  }

  const int lane = t & 63;
  const int wid  = t >> 6;
  const int tok  = blockIdx.x * 4 + wid;
  const int b = tok >> 12, n = tok & (Nn - 1);
  const int d = lane;

  float acc = emb_b[d];
  acc += depth[(size_t)b * Nn + n] * emb_w[d];
  #pragma unroll
  for (int c = 0; c < Cc; ++c)
    acc += prob[((size_t)b * Cc + c) * Nn + n] * emb_w[(1 + c) * 64 + d];

  ws[OFF_XSEQ + (size_t)tok * 64 + d] = acc;

  float mean = wredsum(acc) * (1.f / 64.f);
  float diff = acc - mean;
  float var  = wredsum(diff * diff) * (1.f / 64.f);
  float xn   = diff * rsqrtf(var + EPSv) * ln1g[d] + ln1b[d];

  __syncthreads();   // ipws ready

  float aq = ipb[d], ak = ipb[64 + d], av = ipb[128 + d];
  #pragma unroll 8
  for (int j = 0; j < 64; ++j) {
    float xj = __shfl(xn, j, 64);
    const float* wr = ipws + j * 192;
    aq = fmaf(xj, wr[d],       aq);
    ak = fmaf(xj, wr[64 + d],  ak);
    av = fmaf(xj, wr[128 + d], av);
  }
  const int h = d >> 4, dd = d & 15;
  ushort_t* qb = (ushort_t*)(ws + OFF_QB);
  ushort_t* kb = (ushort_t*)(ws + OFF_KB);
  ushort_t* vb = (ushort_t*)(ws + OFF_VB);
  const size_t base = ((size_t)(b * NHh + h) * Nn + n) * 16 + dd;
  qb[base] = f2bf(aq * 0.25f * LOG2E);
  kb[base] = f2bf(ak);
  vb[base] = f2bf(av);
}

// ---------------------------------------------------------------------------
// K1b: transpose V bf16 [bh][N][16] -> [bh][16][N]
// ---------------------------------------------------------------------------
__global__ __launch_bounds__(256) void k_transpose_v(float* __restrict__ ws)
{
  __shared__ ushort_t tile[256][17];
  const ushort_t* vb = (const ushort_t*)(ws + OFF_VB);
  ushort_t*       vt = (ushort_t*)(ws + OFF_VT);
  const int bh = blockIdx.y;
  const int n0 = blockIdx.x * 256;
  const int t  = threadIdx.x;

  const ushort_t* src = vb + ((size_t)bh * Nn + n0 + t) * 16;
  short8v r0 = *(const short8v*)(src);
  short8v r1 = *(const short8v*)(src + 8);
  #pragma unroll
  for (int i = 0; i < 8; ++i) { tile[t][i] = (ushort_t)r0[i]; tile[t][8 + i] = (ushort_t)r1[i]; }
  __syncthreads();

  const int d = t & 15, seg = t >> 4;
  short8v w0, w1;
  #pragma unroll
  for (int i = 0; i < 8; ++i) {
    w0[i] = (short)tile[seg * 16 + i][d];
    w1[i] = (short)tile[seg * 16 + 8 + i][d];
  }
  ushort_t* dst = vt + ((size_t)bh * 16 + d) * Nn + n0 + seg * 16;
  *(short8v*)(dst)     = w0;
  *(short8v*)(dst + 8) = w1;
}

// ---------------------------------------------------------------------------
// K2: MFMA flash attention, split-K x4. launch_bounds(256,4): VGPR cap 128,
// no spill (round-8 lesson: (256,8) caps VGPR at 32 -> scratch thrash).
// Common path has NO cross-lane ops: in-lane max test only; the uniform
// max tree runs only inside the rare rescale branch (mrun stays uniform
// per-q inductively). l accumulated in 4 regs, folded once at the end.
// ---------------------------------------------------------------------------
__global__ __launch_bounds__(256, 4) void k_attn_mfma(float* __restrict__ ws)
{
  const int lane = threadIdx.x & 63;
  const int wid  = threadIdx.x >> 6;
  const int blk  = blockIdx.x;
  const int seg  = blockIdx.y;              // 0..SEGS-1
  const int bh   = blk >> 6;
  const int qt   = (blk & 63) * 4 + wid;
  const int q0   = qt * 16;
  const int g    = lane >> 4;
  const int qi   = lane & 15;

  const ushort_t* qb = (const ushort_t*)(ws + OFF_QB) + (size_t)bh * Nn * 16;
  const ushort_t* kb = (const ushort_t*)(ws + OFF_KB) + (size_t)bh * Nn * 16;
  const ushort_t* vt = (const ushort_t*)(ws + OFF_VT) + (size_t)bh * 16 * Nn;

  short8v qf = {};
  if (lane < 32)
    qf = *(const short8v*)(qb + (size_t)(q0 + qi) * 16 + g * 8);

  f32x4 O = {0.f, 0.f, 0.f, 0.f};
  float mrun = -INFINITY;
  float lacc[4] = {0.f, 0.f, 0.f, 0.f};
  const f32x4 z4 = {0.f, 0.f, 0.f, 0.f};
  const ushort_t* vrow = vt + (size_t)qi * Nn;

  const int c0 = seg * (Nn / 64 / SEGS);
  #pragma unroll 2
  for (int c = c0; c < c0 + Nn / 64 / SEGS; ++c) {
    const int kb0 = c * 64;
    short8v kf0 = {}, kf1 = {}, kf2 = {}, kf3 = {};
    if (lane < 32) {
      const ushort_t* kr = kb + (size_t)(kb0 + qi) * 16 + g * 8;
      kf0 = *(const short8v*)(kr);
      kf1 = *(const short8v*)(kr + 256);
      kf2 = *(const short8v*)(kr + 512);
      kf3 = *(const short8v*)(kr + 768);
    }
    const ushort_t* vr = vrow + kb0 + 4 * g;
    short4v va00 = *(const short4v*)(vr);
    short4v va01 = *(const short4v*)(vr + 16);
    short4v va10 = *(const short4v*)(vr + 32);
    short4v va11 = *(const short4v*)(vr + 48);

    f32x4 s0 = __builtin_amdgcn_mfma_f32_16x16x32_bf16(kf0, qf, z4, 0, 0, 0);
    f32x4 s1 = __builtin_amdgcn_mfma_f32_16x16x32_bf16(kf1, qf, z4, 0, 0, 0);
    f32x4 s2 = __builtin_amdgcn_mfma_f32_16x16x32_bf16(kf2, qf, z4, 0, 0, 0);
    f32x4 s3 = __builtin_amdgcn_mfma_f32_16x16x32_bf16(kf3, qf, z4, 0, 0, 0);

    // in-lane chunk max (no cross-lane ops in common path)
    float lmax = fmaxf(fmaxf(fmaxf(s0[0], s0[1]), fmaxf(s0[2], s0[3])),
                       fmaxf(fmaxf(s1[0], s1[1]), fmaxf(s1[2], s1[3])));
    lmax = fmaxf(lmax, fmaxf(fmaxf(s2[0], s2[1]), fmaxf(s2[2], s2[3])));
    lmax = fmaxf(lmax, fmaxf(fmaxf(s3[0], s3[1]), fmaxf(s3[2], s3[3])));

    // defer-max (T13), log2 domain; rare branch does the uniform tree
    if (!__all(lmax <= mrun + 11.5f)) {
      float cm = lmax;
      cm = fmaxf(cm, __shfl_xor(cm, 16, 64));
      cm = fmaxf(cm, __shfl_xor(cm, 32, 64));
      const float nm = fmaxf(mrun, cm);
      const float c2 = exp2f(mrun - nm);   // exp2(-inf)=0 handles init
      lacc[0] *= c2; lacc[1] *= c2; lacc[2] *= c2; lacc[3] *= c2;
      O[0] *= c2; O[1] *= c2; O[2] *= c2; O[3] *= c2;
      mrun = nm;
    }

    float p[16];
    #pragma unroll
    for (int r = 0; r < 4; ++r) {
      p[r]      = exp2f(s0[r] - mrun);
      p[4 + r]  = exp2f(s1[r] - mrun);
      p[8 + r]  = exp2f(s2[r] - mrun);
      p[12 + r] = exp2f(s3[r] - mrun);
    }
    #pragma unroll
    for (int i = 0; i < 16; ++i) lacc[i & 3] += p[i];

    union { short8v v; uint_t w[4]; } P0, P1;
    P0.w[0] = cvtpk(p[0], p[1]);   P0.w[1] = cvtpk(p[2], p[3]);
    P0.w[2] = cvtpk(p[4], p[5]);   P0.w[3] = cvtpk(p[6], p[7]);
    P1.w[0] = cvtpk(p[8], p[9]);   P1.w[1] = cvtpk(p[10], p[11]);
    P1.w[2] = cvtpk(p[12], p[13]); P1.w[3] = cvtpk(p[14], p[15]);

    union { short8v v; short4v hh[2]; } VA0, VA1;
    VA0.hh[0] = va00; VA0.hh[1] = va01;
    VA1.hh[0] = va10; VA1.hh[1] = va11;

    O = __builtin_amdgcn_mfma_f32_16x16x32_bf16(VA0.v, P0.v, O, 0, 0, 0);
    O = __builtin_amdgcn_mfma_f32_16x16x32_bf16(VA1.v, P1.v, O, 0, 0, 0);
  }

  float lrun = ((lacc[0] + lacc[1]) + (lacc[2] + lacc[3]));
  lrun += __shfl_xor(lrun, 16, 64);
  lrun += __shfl_xor(lrun, 32, 64);

  const size_t pb = ((size_t)bh * SEGS + seg) * Nn + q0 + qi;
  if (g == 0) { ws[OFF_MP + pb] = mrun; ws[OFF_LP + pb] = lrun; }
  f32x4* op = (f32x4*)(ws + OFF_OP + pb * 16 + g * 4);
  *op = O;
}

// ---------------------------------------------------------------------------
// K3: merge SEGS partials -> out-proj + residual -> x_att -> LN2 -> gate.
// ---------------------------------------------------------------------------
__global__ __launch_bounds__(256) void k_out_ln2(
    const float* __restrict__ aow,  const float* __restrict__ aob,
    const float* __restrict__ ln2g, const float* __restrict__ ln2b,
    const float* __restrict__ gwt,  const float* __restrict__ gbt,
    float* __restrict__ ws)
{
  __shared__ float aows[64 * 64];   // 16 KB
  const int t = threadIdx.x;
  #pragma unroll
  for (int i = 0; i < 4; ++i) {
    const int idx = (i * 256 + t) * 4;
    *(float4*)&aows[idx] = *(const float4*)&aow[idx];
  }

  const int lane = t & 63;
  const int wid  = t >> 6;
  const int tok  = blockIdx.x * 4 + wid;
  const int b = tok >> 12, n = tok & (Nn - 1);
  const int h = lane >> 4, dd = lane & 15;
  const int bh = b * NHh + h;

  float M = -INFINITY;
  #pragma unroll
  for (int s = 0; s < SEGS; ++s)
    M = fmaxf(M, ws[OFF_MP + ((size_t)bh * SEGS + s) * Nn + n]);
  float L = 0.f, oa = 0.f;
  #pragma unroll
  for (int s = 0; s < SEGS; ++s) {
    const size_t pb = ((size_t)bh * SEGS + s) * Nn + n;
    const float c = exp2f(ws[OFF_MP + pb] - M);
    L  = fmaf(ws[OFF_LP + pb], c, L);
    oa = fmaf(ws[OFF_OP + pb * 16 + dd], c, oa);
  }
  const float o = oa / L;

  __syncthreads();   // aows ready

  float acc = aob[lane];
  #pragma unroll 8
  for (int j = 0; j < 64; ++j)
    acc = fmaf(__shfl(o, j, 64), aows[j * 64 + lane], acc);
  const size_t xi = (size_t)tok * 64 + lane;
  const float xa = ws[OFF_XSEQ + xi] + acc;
  ws[OFF_XATT + xi] = xa;

  // LN2 + gate (lane = d)
  float mean = wredsum(xa) * (1.f / 64.f);
  float diff = xa - mean;
  float var  = wredsum(diff * diff) * (1.f / 64.f);
  float xn   = diff * rsqrtf(var + EPSv) * ln2g[lane] + ln2b[lane];

  ushort_t* xn2 = (ushort_t*)(ws + OFF_XN2);
  xn2[xi] = f2bf(xn);

  float ge[4];
  #pragma unroll
  for (int e = 0; e < 4; ++e) ge[e] = xn * gwt[lane * 4 + e];
  #pragma unroll
  for (int off = 32; off > 0; off >>= 1) {
    #pragma unroll
    for (int e = 0; e < 4; ++e) ge[e] += __shfl_xor(ge[e], off, 64);
  }
  #pragma unroll
  for (int e = 0; e < 4; ++e) ge[e] += gbt[e];
  float gm = fmaxf(fmaxf(ge[0], ge[1]), fmaxf(ge[2], ge[3]));
  float gs = 0.f;
  #pragma unroll
  for (int e = 0; e < 4; ++e) { ge[e] = __expf(ge[e] - gm); gs += ge[e]; }
  if (lane == 0) {
    float* gw = ws + OFF_GW + (size_t)tok * 4;
    #pragma unroll
    for (int e = 0; e < 4; ++e) gw[e] = ge[e] / gs;
  }
}

// ---------------------------------------------------------------------------
// K4: GEMM1  h1 = gw .* relu(xn2 @ W1all + b1)   [8192 x 512], K=64, bf16
// ---------------------------------------------------------------------------
__global__ __launch_bounds__(256) void k_gemm1(
    const float* __restrict__ eb1, float* __restrict__ ws)
{
  const int lane = threadIdx.x & 63;
  const int wid  = threadIdx.x >> 6;
  const int qi = lane & 15, g = lane >> 4;
  const int tok0 = blockIdx.x * 64 + wid * 16;
  const int col0 = blockIdx.y * 64;

  const ushort_t* xn2 = (const ushort_t*)(ws + OFF_XN2);
  const ushort_t* w1t = (const ushort_t*)(ws + OFF_W1T);
  const float* gw = ws + OFF_GW;
  ushort_t* h1 = (ushort_t*)(ws + OFF_H1);

  const short8v a0 = *(const short8v*)(xn2 + (size_t)(tok0 + qi) * 64 + g * 8);
  const short8v a1 = *(const short8v*)(xn2 + (size_t)(tok0 + qi) * 64 + 32 + g * 8);

  f32x4 acc[4] = {{0,0,0,0},{0,0,0,0},{0,0,0,0},{0,0,0,0}};
  #pragma unroll
  for (int cf = 0; cf < 4; ++cf) {
    const int col = col0 + cf * 16 + qi;
    const short8v b0 = *(const short8v*)(w1t + (size_t)col * 64 + g * 8);
    const short8v b1 = *(const short8v*)(w1t + (size_t)col * 64 + 32 + g * 8);
    acc[cf] = __builtin_amdgcn_mfma_f32_16x16x32_bf16(a0, b0, acc[cf], 0, 0, 0);
    acc[cf] = __builtin_amdgcn_mfma_f32_16x16x32_bf16(a1, b1, acc[cf], 0, 0, 0);
  }
  #pragma unroll
  for (int cf = 0; cf < 4; ++cf) {
    const int col = col0 + cf * 16 + qi;
    const int e = col >> 7;
    const float bb = eb1[col];
    #pragma unroll
    for (int r = 0; r < 4; ++r) {
      const int tok = tok0 + g * 4 + r;
      float v = fmaxf(acc[cf][r] + bb, 0.f) * gw[(size_t)tok * 4 + e];
      h1[(size_t)tok * 512 + col] = f2bf(v);
    }
  }
}

// ---------------------------------------------------------------------------
// K5: GEMM2 + b2 + residual + proj + sigmoid -> out.
// ---------------------------------------------------------------------------
__global__ __launch_bounds__(64) void k_gemm2f(
    const float* __restrict__ b2, const float* __restrict__ pw,
    const float* __restrict__ pbv, const float* __restrict__ ws,
    float* __restrict__ out)
{
  const int lane = threadIdx.x;
  const int qi = lane & 15, g = lane >> 4;
  const int tok0 = blockIdx.x * 16;

  const ushort_t* h1  = (const ushort_t*)(ws + OFF_H1);
  const ushort_t* w2t = (const ushort_t*)(ws + OFF_W2T);

  f32x4 acc[4] = {{0,0,0,0},{0,0,0,0},{0,0,0,0},{0,0,0,0}};
  #pragma unroll 4
  for (int s = 0; s < 16; ++s) {
    const short8v a = *(const short8v*)(h1 + (size_t)(tok0 + qi) * 512 + s * 32 + g * 8);
    #pragma unroll
    for (int cf = 0; cf < 4; ++cf) {
      const short8v b = *(const short8v*)(w2t + (size_t)(cf * 16 + qi) * 512 + s * 32 + g * 8);
      acc[cf] = __builtin_amdgcn_mfma_f32_16x16x32_bf16(a, b, acc[cf], 0, 0, 0);
    }
  }

  const float* xatt = ws + OFF_XATT;
  const float* gw   = ws + OFF_GW;

  float gwv[4][4];   // [r][e]
  #pragma unroll
  for (int r = 0; r < 4; ++r) {
    const int tok = tok0 + g * 4 + r;
    #pragma unroll
    for (int e = 0; e < 4; ++e) gwv[r][e] = gw[(size_t)tok * 4 + e];
  }

  float part[4] = {0.f, 0.f, 0.f, 0.f};
  #pragma unroll
  for (int cf = 0; cf < 4; ++cf) {
    const int d = cf * 16 + qi;
    const float pwd = pw[d];
    const float b20 = b2[d], b21 = b2[64 + d], b22 = b2[128 + d], b23 = b2[192 + d];
    #pragma unroll
    for (int r = 0; r < 4; ++r) {
      const int tok = tok0 + g * 4 + r;
      const float bias2 = gwv[r][0]*b20 + gwv[r][1]*b21 + gwv[r][2]*b22 + gwv[r][3]*b23;
      const float xo = xatt[(size_t)tok * 64 + d] + acc[cf][r] + bias2;
      part[r] = fmaf(xo, pwd, part[r]);
    }
  }
  #pragma unroll
  for (int r = 0; r < 4; ++r) {
    #pragma unroll
    for (int mask = 8; mask > 0; mask >>= 1)
      part[r] += __shfl_xor(part[r], mask, 64);
  }
  if (qi == 0) {
    const float pb0 = pbv[0];
    #pragma unroll
    for (int r = 0; r < 4; ++r)
      out[tok0 + g * 4 + r] = 1.f / (1.f + __expf(-(part[r] + pb0)));
  }
}

} // namespace

extern "C" void kernel_launch(void* const* d_in, const int* in_sizes, int n_in,
                              void* d_out, int out_size, void* d_ws, size_t ws_size,
                              hipStream_t stream) {
  const float* depth = (const float*)d_in[0];
  const float* prob  = (const float*)d_in[1];
  const float* emb_w = (const float*)d_in[2];
  const float* emb_b = (const float*)d_in[3];
  const float* ipw   = (const float*)d_in[4];
  const float* ipb   = (const float*)d_in[5];
  const float* aow   = (const float*)d_in[6];
  const float* aob   = (const float*)d_in[7];
  const float* ln1g  = (const float*)d_in[8];
  const float* ln1b  = (const float*)d_in[9];
  const float* ln2g  = (const float*)d_in[10];
  const float* ln2b  = (const float*)d_in[11];
  const float* w1    = (const float*)d_in[12];
  const float* b1    = (const float*)d_in[13];
  const float* w2    = (const float*)d_in[14];
  const float* b2    = (const float*)d_in[15];
  const float* gatew = (const float*)d_in[16];
  const float* gateb = (const float*)d_in[17];
  const float* projw = (const float*)d_in[18];
  const float* projb = (const float*)d_in[19];
  float* out = (float*)d_out;
  float* wsf = (float*)d_ws;

  k_wcvt<<<128, 256, 0, stream>>>(w1, w2, wsf);
  k_embed_qkv<<<Bb * Nn / 4, 256, 0, stream>>>(depth, prob, emb_w, emb_b,
                                               ipw, ipb, ln1g, ln1b, wsf);
  k_transpose_v<<<dim3(Nn / 256, Bb * NHh), 256, 0, stream>>>(wsf);
  k_attn_mfma<<<dim3(Bb * NHh * 64, SEGS), 256, 0, stream>>>(wsf);
  k_out_ln2<<<Bb * Nn / 4, 256, 0, stream>>>(aow, aob, ln2g, ln2b,
                                             gatew, gateb, wsf);
  k_gemm1<<<dim3(Bb * Nn / 64, 8), 256, 0, stream>>>(b1, wsf);
  k_gemm2f<<<Bb * Nn / 16, 64, 0, stream>>>(b2, projw, projb, wsf, out);
}

// Round 10
// 213.001 us; speedup vs baseline: 1.2054x; 1.0877x over previous
//
#include <hip/hip_runtime.h>
#include <math.h>

#define DEV __device__ __forceinline__

namespace {

constexpr int Bb  = 2;
constexpr int Nn  = 4096;   // H*W tokens per batch
constexpr int Cc  = 19;     // prob channels
constexpr int NHh = 4;      // heads
constexpr int SEGS = 2;     // attention split-K segments (r7-proven; 4 regressed)
constexpr float EPSv = 1e-5f;
constexpr float LOG2E = 1.4426950408889634f;

typedef __attribute__((ext_vector_type(4))) short short4v;
typedef __attribute__((ext_vector_type(8))) short short8v;
typedef __attribute__((ext_vector_type(4))) float f32x4;
typedef unsigned short ushort_t;
typedef unsigned int uint_t;

// workspace layout (float offsets)
constexpr size_t QKV_F    = (size_t)Bb * Nn * 32;           // 262144
constexpr size_t OFF_XSEQ = 0;                              // B*N*64 f32
constexpr size_t OFF_XATT = OFF_XSEQ + (size_t)Bb*Nn*64;
constexpr size_t OFF_QB   = OFF_XATT + (size_t)Bb*Nn*64;    // bf16 [B*NH][N][16]
constexpr size_t OFF_KB   = OFF_QB + QKV_F;
constexpr size_t OFF_VB   = OFF_KB + QKV_F;
constexpr size_t OFF_VT   = OFF_VB + QKV_F;                 // bf16 [B*NH][16][N]
constexpr size_t OFF_MP   = OFF_VT + QKV_F;                 // [bh][seg][q]
constexpr size_t OFF_LP   = OFF_MP + (size_t)Bb*NHh*SEGS*Nn;
constexpr size_t OFF_OP   = OFF_LP + (size_t)Bb*NHh*SEGS*Nn; // [bh][seg][q][16]
constexpr size_t OFF_XN2  = OFF_OP + (size_t)Bb*NHh*SEGS*Nn*16; // bf16 [8192][64]
constexpr size_t OFF_GW   = OFF_XN2 + (size_t)Bb*Nn*32;     // f32 [8192][4]
constexpr size_t OFF_W1T  = OFF_GW + (size_t)Bb*Nn*4;       // bf16 [512][64]
constexpr size_t OFF_W2T  = OFF_W1T + 16384;                // bf16 [64][512]

DEV float wredsum(float x) {
  #pragma unroll
  for (int off = 32; off > 0; off >>= 1) x += __shfl_xor(x, off, 64);
  return x;
}
// f32 -> bf16 RNE via bit ops (finite inputs only)
DEV ushort_t f2bf(float x) {
  uint_t u = __builtin_bit_cast(uint_t, x);
  u += 0x7fffu + ((u >> 16) & 1u);
  return (ushort_t)(u >> 16);
}
// packed 2xbf16 via HW cvt_pk (a in low half), RNE
DEV uint_t cvtpk(float a, float b) {
  uint_t r;
  asm("v_cvt_pk_bf16_f32 %0, %1, %2" : "=v"(r) : "v"(a), "v"(b));
  return r;
}

// ---------------------------------------------------------------------------
// K1: embed -> x_seq -> LN1 -> QKV (bf16; Q prescaled by 0.25*log2e).
// Blocks 0..127 additionally convert expert weights to bf16 tables (fused
// former k_wcvt; w1t/w2t consumed only by k_moe2, launched later).
// ---------------------------------------------------------------------------
__global__ __launch_bounds__(256) void k_embed_qkv(
    const float* __restrict__ depth, const float* __restrict__ prob,
    const float* __restrict__ emb_w, const float* __restrict__ emb_b,
    const float* __restrict__ ipw,   const float* __restrict__ ipb,
    const float* __restrict__ ln1g,  const float* __restrict__ ln1b,
    const float* __restrict__ w1,    const float* __restrict__ w2,
    float* __restrict__ ws)
{
  __shared__ float ipws[64 * 192];   // 48 KB

  const int t = threadIdx.x;

  if (blockIdx.x < 128) {            // fused weight conversion
    const int idx = blockIdx.x * 256 + t;   // 0..32767
    ushort_t* w1t = (ushort_t*)(ws + OFF_W1T);
    ushort_t* w2t = (ushort_t*)(ws + OFF_W2T);
    {
      const int col = idx >> 6, k = idx & 63;
      const int e = col >> 7, h = col & 127;
      w1t[idx] = f2bf(w1[((size_t)e * 64 + k) * 128 + h]);
    }
    {
      const int d = idx >> 9, kk = idx & 511;
      const int e = kk >> 7, h = kk & 127;
      w2t[idx] = f2bf(w2[((size_t)e * 128 + h) * 64 + d]);
    }
  }

  #pragma unroll
  for (int i = 0; i < 12; ++i) {
    const int idx = (i * 256 + t) * 4;
    *(float4*)&ipws[idx] = *(const float4*)&ipw[idx];
  }

  const int lane = t & 63;
  const int wid  = t >> 6;
  const int tok  = blockIdx.x * 4 + wid;
  const int b = tok >> 12, n = tok & (Nn - 1);
  const int d = lane;

  float acc = emb_b[d];
  acc += depth[(size_t)b * Nn + n] * emb_w[d];
  #pragma unroll
  for (int c = 0; c < Cc; ++c)
    acc += prob[((size_t)b * Cc + c) * Nn + n] * emb_w[(1 + c) * 64 + d];

  ws[OFF_XSEQ + (size_t)tok * 64 + d] = acc;

  float mean = wredsum(acc) * (1.f / 64.f);
  float diff = acc - mean;
  float var  = wredsum(diff * diff) * (1.f / 64.f);
  float xn   = diff * rsqrtf(var + EPSv) * ln1g[d] + ln1b[d];

  __syncthreads();   // ipws ready

  float aq = ipb[d], ak = ipb[64 + d], av = ipb[128 + d];
  #pragma unroll 8
  for (int j = 0; j < 64; ++j) {
    float xj = __shfl(xn, j, 64);
    const float* wr = ipws + j * 192;
    aq = fmaf(xj, wr[d],       aq);
    ak = fmaf(xj, wr[64 + d],  ak);
    av = fmaf(xj, wr[128 + d], av);
  }
  const int h = d >> 4, dd = d & 15;
  ushort_t* qb = (ushort_t*)(ws + OFF_QB);
  ushort_t* kb = (ushort_t*)(ws + OFF_KB);
  ushort_t* vb = (ushort_t*)(ws + OFF_VB);
  const size_t base = ((size_t)(b * NHh + h) * Nn + n) * 16 + dd;
  qb[base] = f2bf(aq * 0.25f * LOG2E);
  kb[base] = f2bf(ak);
  vb[base] = f2bf(av);
}

// ---------------------------------------------------------------------------
// K1b: transpose V bf16 [bh][N][16] -> [bh][16][N]
// ---------------------------------------------------------------------------
__global__ __launch_bounds__(256) void k_transpose_v(float* __restrict__ ws)
{
  __shared__ ushort_t tile[256][17];
  const ushort_t* vb = (const ushort_t*)(ws + OFF_VB);
  ushort_t*       vt = (ushort_t*)(ws + OFF_VT);
  const int bh = blockIdx.y;
  const int n0 = blockIdx.x * 256;
  const int t  = threadIdx.x;

  const ushort_t* src = vb + ((size_t)bh * Nn + n0 + t) * 16;
  short8v r0 = *(const short8v*)(src);
  short8v r1 = *(const short8v*)(src + 8);
  #pragma unroll
  for (int i = 0; i < 8; ++i) { tile[t][i] = (ushort_t)r0[i]; tile[t][8 + i] = (ushort_t)r1[i]; }
  __syncthreads();

  const int d = t & 15, seg = t >> 4;
  short8v w0, w1;
  #pragma unroll
  for (int i = 0; i < 8; ++i) {
    w0[i] = (short)tile[seg * 16 + i][d];
    w1[i] = (short)tile[seg * 16 + 8 + i][d];
  }
  ushort_t* dst = vt + ((size_t)bh * 16 + d) * Nn + n0 + seg * 16;
  *(short8v*)(dst)     = w0;
  *(short8v*)(dst + 8) = w1;
}

// ---------------------------------------------------------------------------
// K2: MFMA flash attention, split-K x2 (r7-proven config) with in-lane
// max test (cross-lane tree only in rare rescale branch) and lacc[4].
// ---------------------------------------------------------------------------
__global__ __launch_bounds__(256, 4) void k_attn_mfma(float* __restrict__ ws)
{
  const int lane = threadIdx.x & 63;
  const int wid  = threadIdx.x >> 6;
  const int blk  = blockIdx.x;
  const int seg  = blockIdx.y;              // 0..SEGS-1
  const int bh   = blk >> 6;
  const int qt   = (blk & 63) * 4 + wid;
  const int q0   = qt * 16;
  const int g    = lane >> 4;
  const int qi   = lane & 15;

  const ushort_t* qb = (const ushort_t*)(ws + OFF_QB) + (size_t)bh * Nn * 16;
  const ushort_t* kb = (const ushort_t*)(ws + OFF_KB) + (size_t)bh * Nn * 16;
  const ushort_t* vt = (const ushort_t*)(ws + OFF_VT) + (size_t)bh * 16 * Nn;

  short8v qf = {};
  if (lane < 32)
    qf = *(const short8v*)(qb + (size_t)(q0 + qi) * 16 + g * 8);

  f32x4 O = {0.f, 0.f, 0.f, 0.f};
  float mrun = -INFINITY;
  float lacc[4] = {0.f, 0.f, 0.f, 0.f};
  const f32x4 z4 = {0.f, 0.f, 0.f, 0.f};
  const ushort_t* vrow = vt + (size_t)qi * Nn;

  const int c0 = seg * (Nn / 64 / SEGS);
  #pragma unroll 2
  for (int c = c0; c < c0 + Nn / 64 / SEGS; ++c) {
    const int kb0 = c * 64;
    short8v kf0 = {}, kf1 = {}, kf2 = {}, kf3 = {};
    if (lane < 32) {
      const ushort_t* kr = kb + (size_t)(kb0 + qi) * 16 + g * 8;
      kf0 = *(const short8v*)(kr);
      kf1 = *(const short8v*)(kr + 256);
      kf2 = *(const short8v*)(kr + 512);
      kf3 = *(const short8v*)(kr + 768);
    }
    const ushort_t* vr = vrow + kb0 + 4 * g;
    short4v va00 = *(const short4v*)(vr);
    short4v va01 = *(const short4v*)(vr + 16);
    short4v va10 = *(const short4v*)(vr + 32);
    short4v va11 = *(const short4v*)(vr + 48);

    f32x4 s0 = __builtin_amdgcn_mfma_f32_16x16x32_bf16(kf0, qf, z4, 0, 0, 0);
    f32x4 s1 = __builtin_amdgcn_mfma_f32_16x16x32_bf16(kf1, qf, z4, 0, 0, 0);
    f32x4 s2 = __builtin_amdgcn_mfma_f32_16x16x32_bf16(kf2, qf, z4, 0, 0, 0);
    f32x4 s3 = __builtin_amdgcn_mfma_f32_16x16x32_bf16(kf3, qf, z4, 0, 0, 0);

    // in-lane chunk max (no cross-lane ops in common path)
    float lmax = fmaxf(fmaxf(fmaxf(s0[0], s0[1]), fmaxf(s0[2], s0[3])),
                       fmaxf(fmaxf(s1[0], s1[1]), fmaxf(s1[2], s1[3])));
    lmax = fmaxf(lmax, fmaxf(fmaxf(s2[0], s2[1]), fmaxf(s2[2], s2[3])));
    lmax = fmaxf(lmax, fmaxf(fmaxf(s3[0], s3[1]), fmaxf(s3[2], s3[3])));

    // defer-max (T13), log2 domain; rare branch does the uniform tree
    if (!__all(lmax <= mrun + 11.5f)) {
      float cm = lmax;
      cm = fmaxf(cm, __shfl_xor(cm, 16, 64));
      cm = fmaxf(cm, __shfl_xor(cm, 32, 64));
      const float nm = fmaxf(mrun, cm);
      const float c2 = exp2f(mrun - nm);   // exp2(-inf)=0 handles init
      lacc[0] *= c2; lacc[1] *= c2; lacc[2] *= c2; lacc[3] *= c2;
      O[0] *= c2; O[1] *= c2; O[2] *= c2; O[3] *= c2;
      mrun = nm;
    }

    float p[16];
    #pragma unroll
    for (int r = 0; r < 4; ++r) {
      p[r]      = exp2f(s0[r] - mrun);
      p[4 + r]  = exp2f(s1[r] - mrun);
      p[8 + r]  = exp2f(s2[r] - mrun);
      p[12 + r] = exp2f(s3[r] - mrun);
    }
    #pragma unroll
    for (int i = 0; i < 16; ++i) lacc[i & 3] += p[i];

    union { short8v v; uint_t w[4]; } P0, P1;
    P0.w[0] = cvtpk(p[0], p[1]);   P0.w[1] = cvtpk(p[2], p[3]);
    P0.w[2] = cvtpk(p[4], p[5]);   P0.w[3] = cvtpk(p[6], p[7]);
    P1.w[0] = cvtpk(p[8], p[9]);   P1.w[1] = cvtpk(p[10], p[11]);
    P1.w[2] = cvtpk(p[12], p[13]); P1.w[3] = cvtpk(p[14], p[15]);

    union { short8v v; short4v hh[2]; } VA0, VA1;
    VA0.hh[0] = va00; VA0.hh[1] = va01;
    VA1.hh[0] = va10; VA1.hh[1] = va11;

    O = __builtin_amdgcn_mfma_f32_16x16x32_bf16(VA0.v, P0.v, O, 0, 0, 0);
    O = __builtin_amdgcn_mfma_f32_16x16x32_bf16(VA1.v, P1.v, O, 0, 0, 0);
  }

  float lrun = ((lacc[0] + lacc[1]) + (lacc[2] + lacc[3]));
  lrun += __shfl_xor(lrun, 16, 64);
  lrun += __shfl_xor(lrun, 32, 64);

  const size_t pb = ((size_t)bh * SEGS + seg) * Nn + q0 + qi;
  if (g == 0) { ws[OFF_MP + pb] = mrun; ws[OFF_LP + pb] = lrun; }
  f32x4* op = (f32x4*)(ws + OFF_OP + pb * 16 + g * 4);
  *op = O;
}

// ---------------------------------------------------------------------------
// K3: merge SEGS partials -> out-proj + residual -> x_att -> LN2 -> gate.
// ---------------------------------------------------------------------------
__global__ __launch_bounds__(256) void k_out_ln2(
    const float* __restrict__ aow,  const float* __restrict__ aob,
    const float* __restrict__ ln2g, const float* __restrict__ ln2b,
    const float* __restrict__ gwt,  const float* __restrict__ gbt,
    float* __restrict__ ws)
{
  __shared__ float aows[64 * 64];   // 16 KB
  const int t = threadIdx.x;
  #pragma unroll
  for (int i = 0; i < 4; ++i) {
    const int idx = (i * 256 + t) * 4;
    *(float4*)&aows[idx] = *(const float4*)&aow[idx];
  }

  const int lane = t & 63;
  const int wid  = t >> 6;
  const int tok  = blockIdx.x * 4 + wid;
  const int b = tok >> 12, n = tok & (Nn - 1);
  const int h = lane >> 4, dd = lane & 15;
  const int bh = b * NHh + h;

  float M = -INFINITY;
  #pragma unroll
  for (int s = 0; s < SEGS; ++s)
    M = fmaxf(M, ws[OFF_MP + ((size_t)bh * SEGS + s) * Nn + n]);
  float L = 0.f, oa = 0.f;
  #pragma unroll
  for (int s = 0; s < SEGS; ++s) {
    const size_t pb = ((size_t)bh * SEGS + s) * Nn + n;
    const float c = exp2f(ws[OFF_MP + pb] - M);
    L  = fmaf(ws[OFF_LP + pb], c, L);
    oa = fmaf(ws[OFF_OP + pb * 16 + dd], c, oa);
  }
  const float o = oa / L;

  __syncthreads();   // aows ready

  float acc = aob[lane];
  #pragma unroll 8
  for (int j = 0; j < 64; ++j)
    acc = fmaf(__shfl(o, j, 64), aows[j * 64 + lane], acc);
  const size_t xi = (size_t)tok * 64 + lane;
  const float xa = ws[OFF_XSEQ + xi] + acc;
  ws[OFF_XATT + xi] = xa;

  // LN2 + gate (lane = d)
  float mean = wredsum(xa) * (1.f / 64.f);
  float diff = xa - mean;
  float var  = wredsum(diff * diff) * (1.f / 64.f);
  float xn   = diff * rsqrtf(var + EPSv) * ln2g[lane] + ln2b[lane];

  ushort_t* xn2 = (ushort_t*)(ws + OFF_XN2);
  xn2[xi] = f2bf(xn);

  float ge[4];
  #pragma unroll
  for (int e = 0; e < 4; ++e) ge[e] = xn * gwt[lane * 4 + e];
  #pragma unroll
  for (int off = 32; off > 0; off >>= 1) {
    #pragma unroll
    for (int e = 0; e < 4; ++e) ge[e] += __shfl_xor(ge[e], off, 64);
  }
  #pragma unroll
  for (int e = 0; e < 4; ++e) ge[e] += gbt[e];
  float gm = fmaxf(fmaxf(ge[0], ge[1]), fmaxf(ge[2], ge[3]));
  float gs = 0.f;
  #pragma unroll
  for (int e = 0; e < 4; ++e) { ge[e] = __expf(ge[e] - gm); gs += ge[e]; }
  if (lane == 0) {
    float* gw = ws + OFF_GW + (size_t)tok * 4;
    #pragma unroll
    for (int e = 0; e < 4; ++e) gw[e] = ge[e] / gs;
  }
}

// ---------------------------------------------------------------------------
// K4: fused MoE. Block = 32 tokens, 4 waves.
// Phase A (gemm1): wave = 16 tok x 256 cols, K=64; h1 -> LDS (pad 520 -> only
// 2-way bank aliasing on the stride-row reads, free per m136).
// Phase B (gemm2): wave = 16 tok x 32 d, K=512 from LDS; epilogue adds
// gw.b2 bias + residual, proj-reduces, sigmoid, stores.
// ---------------------------------------------------------------------------
__global__ __launch_bounds__(256) void k_moe2(
    const float* __restrict__ eb1, const float* __restrict__ b2,
    const float* __restrict__ pw,  const float* __restrict__ pbv,
    float* __restrict__ ws,        float* __restrict__ out)
{
  __shared__ ushort_t h1s[32][520];   // 33.3 KB
  __shared__ float gws[32][4];
  __shared__ float partial[32][2];

  const int t = threadIdx.x;
  const int lane = t & 63, wid = t >> 6;
  const int qi = lane & 15, g = lane >> 4;
  const int tokB = blockIdx.x * 32;

  if (t < 128)
    gws[t >> 2][t & 3] = ws[OFF_GW + (size_t)(tokB + (t >> 2)) * 4 + (t & 3)];

  const int th   = wid >> 1;            // token half 0/1
  const int tok0 = tokB + th * 16;
  const int col0 = (wid & 1) * 256;

  const ushort_t* xn2 = (const ushort_t*)(ws + OFF_XN2);
  const ushort_t* w1t = (const ushort_t*)(ws + OFF_W1T);
  const ushort_t* w2t = (const ushort_t*)(ws + OFF_W2T);

  const short8v a0 = *(const short8v*)(xn2 + (size_t)(tok0 + qi) * 64 + g * 8);
  const short8v a1 = *(const short8v*)(xn2 + (size_t)(tok0 + qi) * 64 + 32 + g * 8);

  __syncthreads();   // gws ready

  const f32x4 z4 = {0.f, 0.f, 0.f, 0.f};
  #pragma unroll 4
  for (int cf = 0; cf < 16; ++cf) {
    const int col = col0 + cf * 16 + qi;
    const short8v b0 = *(const short8v*)(w1t + (size_t)col * 64 + g * 8);
    const short8v b1 = *(const short8v*)(w1t + (size_t)col * 64 + 32 + g * 8);
    f32x4 acc = __builtin_amdgcn_mfma_f32_16x16x32_bf16(a0, b0, z4, 0, 0, 0);
    acc = __builtin_amdgcn_mfma_f32_16x16x32_bf16(a1, b1, acc, 0, 0, 0);
    const int e = col >> 7;
    const float bb = eb1[col];
    #pragma unroll
    for (int r = 0; r < 4; ++r) {
      const int ltok = th * 16 + g * 4 + r;
      const float v = fmaxf(acc[r] + bb, 0.f) * gws[ltok][e];
      h1s[ltok][col] = f2bf(v);
    }
  }

  __syncthreads();   // h1s complete

  // gemm2: this wave covers toks tok0..tok0+15, d in [dbase, dbase+32)
  const int dbase = (wid & 1) * 32;
  f32x4 acc2[2] = {{0,0,0,0},{0,0,0,0}};
  #pragma unroll 4
  for (int s = 0; s < 16; ++s) {
    const short8v a = *(const short8v*)&h1s[th * 16 + qi][s * 32 + g * 8];
    #pragma unroll
    for (int df = 0; df < 2; ++df) {
      const int d = dbase + df * 16 + qi;
      const short8v b = *(const short8v*)(w2t + (size_t)d * 512 + s * 32 + g * 8);
      acc2[df] = __builtin_amdgcn_mfma_f32_16x16x32_bf16(a, b, acc2[df], 0, 0, 0);
    }
  }

  const float* xatt = ws + OFF_XATT;
  float part[4] = {0.f, 0.f, 0.f, 0.f};
  #pragma unroll
  for (int df = 0; df < 2; ++df) {
    const int d = dbase + df * 16 + qi;
    const float pwd = pw[d];
    const float b20 = b2[d], b21 = b2[64 + d], b22 = b2[128 + d], b23 = b2[192 + d];
    #pragma unroll
    for (int r = 0; r < 4; ++r) {
      const int ltok = th * 16 + g * 4 + r;
      const float* gwr = gws[ltok];
      const float bias2 = gwr[0]*b20 + gwr[1]*b21 + gwr[2]*b22 + gwr[3]*b23;
      const float xo = xatt[(size_t)(tokB + ltok) * 64 + d] + acc2[df][r] + bias2;
      part[r] = fmaf(xo, pwd, part[r]);
    }
  }
  #pragma unroll
  for (int r = 0; r < 4; ++r) {
    #pragma unroll
    for (int mask = 8; mask > 0; mask >>= 1)
      part[r] += __shfl_xor(part[r], mask, 64);
  }
  if (qi == 0) {
    #pragma unroll
    for (int r = 0; r < 4; ++r)
      partial[th * 16 + g * 4 + r][wid & 1] = part[r];
  }
  __syncthreads();
  if (t < 32) {
    const float v = partial[t][0] + partial[t][1] + 0.f;
    out[tokB + t] = 1.f / (1.f + __expf(-(v + pbv[0])));
  }
}

} // namespace

extern "C" void kernel_launch(void* const* d_in, const int* in_sizes, int n_in,
                              void* d_out, int out_size, void* d_ws, size_t ws_size,
                              hipStream_t stream) {
  const float* depth = (const float*)d_in[0];
  const float* prob  = (const float*)d_in[1];
  const float* emb_w = (const float*)d_in[2];
  const float* emb_b = (const float*)d_in[3];
  const float* ipw   = (const float*)d_in[4];
  const float* ipb   = (const float*)d_in[5];
  const float* aow   = (const float*)d_in[6];
  const float* aob   = (const float*)d_in[7];
  const float* ln1g  = (const float*)d_in[8];
  const float* ln1b  = (const float*)d_in[9];
  const float* ln2g  = (const float*)d_in[10];
  const float* ln2b  = (const float*)d_in[11];
  const float* w1    = (const float*)d_in[12];
  const float* b1    = (const float*)d_in[13];
  const float* w2    = (const float*)d_in[14];
  const float* b2    = (const float*)d_in[15];
  const float* gatew = (const float*)d_in[16];
  const float* gateb = (const float*)d_in[17];
  const float* projw = (const float*)d_in[18];
  const float* projb = (const float*)d_in[19];
  float* out = (float*)d_out;
  float* wsf = (float*)d_ws;

  k_embed_qkv<<<Bb * Nn / 4, 256, 0, stream>>>(depth, prob, emb_w, emb_b,
                                               ipw, ipb, ln1g, ln1b, w1, w2, wsf);
  k_transpose_v<<<dim3(Nn / 256, Bb * NHh), 256, 0, stream>>>(wsf);
  k_attn_mfma<<<dim3(Bb * NHh * 64, SEGS), 256, 0, stream>>>(wsf);
  k_out_ln2<<<Bb * Nn / 4, 256, 0, stream>>>(aow, aob, ln2g, ln2b,
                                             gatew, gateb, wsf);
  k_moe2<<<Bb * Nn / 32, 256, 0, stream>>>(b1, b2, projw, projb, wsf, out);
}